// Round 1
// baseline (39.299 us; speedup 1.0000x reference)
//
#include <hip/hip_runtime.h>

#define N_VOCAB 50400
#define D_MODEL 4096
#define SHARDS  8
#define SEQ     2048
#define BATCH   2
#define PER_IN  6300   // N_VOCAB / SHARDS

// Kernel 1: precompute B[s][d] = sum_{s'<s} kernel[s'*PER_IN + PER_IN-1][d]
//                              + sum_{s'>s} kernel[s'*PER_IN][d]  + SHARDS*bias[d]
__global__ void boundary_sums_kernel(const float* __restrict__ kern,
                                     const float* __restrict__ bias,
                                     float* __restrict__ bsum) {
    int d = blockIdx.x * blockDim.x + threadIdx.x;
    if (d >= D_MODEL) return;
    float first[SHARDS], last[SHARDS];
#pragma unroll
    for (int s = 0; s < SHARDS; ++s) {
        first[s] = kern[(size_t)(s * PER_IN) * D_MODEL + d];
        last[s]  = kern[(size_t)(s * PER_IN + PER_IN - 1) * D_MODEL + d];
    }
    float b8 = (float)SHARDS * bias[d];
#pragma unroll
    for (int s = 0; s < SHARDS; ++s) {
        float acc = b8;
#pragma unroll
        for (int sp = 0; sp < SHARDS; ++sp) {
            if (sp < s)      acc += last[sp];
            else if (sp > s) acc += first[sp];
        }
        bsum[s * D_MODEL + d] = acc;
    }
}

// Kernel 2: one block per (b,t) token. out = kernel[x] + B[x/PER_IN] + pos_flat[t].
__global__ __launch_bounds__(256)
void embed_gather_kernel(const int* __restrict__ x,
                         const float* __restrict__ kern,
                         const float* __restrict__ pos,   // flat [SEQ*D_MODEL]
                         const float* __restrict__ bsum,  // [SHARDS][D_MODEL]
                         float* __restrict__ out) {
    const int token = blockIdx.x;          // b*SEQ + t
    const int t     = token & (SEQ - 1);   // SEQ = 2048 is pow2
    const int tid   = threadIdx.x;

    const int row = x[token];              // 0 <= row < N_VOCAB (scalar, cached)
    const int s   = row / PER_IN;          // shard containing row

    const float4* __restrict__ krow = (const float4*)(kern + (size_t)row * D_MODEL);
    const float4* __restrict__ prow = (const float4*)(pos  + (size_t)t   * D_MODEL);
    const float4* __restrict__ brow = (const float4*)(bsum + (size_t)s   * D_MODEL);
    float4* __restrict__       orow = (float4*)(out + (size_t)token * D_MODEL);

#pragma unroll
    for (int k = 0; k < (D_MODEL / 4) / 256; ++k) {   // 4 iterations
        const int i = tid + k * 256;
        float4 a = krow[i];
        float4 p = prow[i];
        float4 b = brow[i];
        float4 o;
        o.x = a.x + b.x + p.x;
        o.y = a.y + b.y + p.y;
        o.z = a.z + b.z + p.z;
        o.w = a.w + b.w + p.w;
        orow[i] = o;
    }
}

extern "C" void kernel_launch(void* const* d_in, const int* in_sizes, int n_in,
                              void* d_out, int out_size, void* d_ws, size_t ws_size,
                              hipStream_t stream) {
    const int*   x    = (const int*)  d_in[0];   // [BATCH, SEQ]
    const float* kern = (const float*)d_in[1];   // [N_VOCAB, D_MODEL]
    const float* bias = (const float*)d_in[2];   // [D_MODEL]
    const float* pos  = (const float*)d_in[3];   // [SHARDS, SEQ, PER_OUT] == flat [SEQ*D_MODEL]

    float* out  = (float*)d_out;                 // [BATCH, SEQ, D_MODEL]
    float* bsum = (float*)d_ws;                  // [SHARDS][D_MODEL] = 128 KB

    boundary_sums_kernel<<<(D_MODEL + 255) / 256, 256, 0, stream>>>(kern, bias, bsum);

    embed_gather_kernel<<<BATCH * SEQ, 256, 0, stream>>>(x, kern, pos, bsum, out);
}

// Round 3
// 34.385 us; speedup vs baseline: 1.1429x; 1.1429x over previous
//
#include <hip/hip_runtime.h>

#define N_VOCAB 50400
#define D_MODEL 4096
#define SHARDS  8
#define SEQ     2048
#define BATCH   2
#define PER_IN  6300   // N_VOCAB / SHARDS

typedef float f4 __attribute__((ext_vector_type(4)));   // native vector: OK for nontemporal builtins

// Kernel 1: precompute B[s][d] = sum_{s'<s} kernel[s'*PER_IN + PER_IN-1][d]
//                              + sum_{s'>s} kernel[s'*PER_IN][d]  + SHARDS*bias[d]
__global__ void boundary_sums_kernel(const float* __restrict__ kern,
                                     const float* __restrict__ bias,
                                     float* __restrict__ bsum) {
    int d = blockIdx.x * blockDim.x + threadIdx.x;
    if (d >= D_MODEL) return;
    float first[SHARDS], last[SHARDS];
#pragma unroll
    for (int s = 0; s < SHARDS; ++s) {
        first[s] = kern[(size_t)(s * PER_IN) * D_MODEL + d];
        last[s]  = kern[(size_t)(s * PER_IN + PER_IN - 1) * D_MODEL + d];
    }
    float b8 = (float)SHARDS * bias[d];
#pragma unroll
    for (int s = 0; s < SHARDS; ++s) {
        float acc = b8;
#pragma unroll
        for (int sp = 0; sp < SHARDS; ++sp) {
            if (sp < s)      acc += last[sp];
            else if (sp > s) acc += first[sp];
        }
        bsum[s * D_MODEL + d] = acc;
    }
}

// Kernel 2: one block per sequence position t; handles BOTH batch rows.
// out[b,t,:] = kernel[x[b,t]] + B[x[b,t]/PER_IN] + pos_flat[t,:]
__global__ __launch_bounds__(256)
void embed_gather_kernel(const int* __restrict__ x,
                         const float* __restrict__ kern,
                         const float* __restrict__ pos,   // flat [SEQ*D_MODEL]
                         const float* __restrict__ bsum,  // [SHARDS][D_MODEL]
                         float* __restrict__ out) {
    const int t   = blockIdx.x;
    const int tid = threadIdx.x;

    const int row0 = x[t];           // batch 0
    const int row1 = x[SEQ + t];     // batch 1
    const int s0 = row0 / PER_IN;
    const int s1 = row1 / PER_IN;

    const f4* __restrict__ k0 = (const f4*)(kern + (size_t)row0 * D_MODEL);
    const f4* __restrict__ k1 = (const f4*)(kern + (size_t)row1 * D_MODEL);
    const f4* __restrict__ pr = (const f4*)(pos  + (size_t)t    * D_MODEL);
    const f4* __restrict__ b0 = (const f4*)(bsum + (size_t)s0   * D_MODEL);
    const f4* __restrict__ b1 = (const f4*)(bsum + (size_t)s1   * D_MODEL);
    f4* __restrict__ o0 = (f4*)(out + (size_t)t         * D_MODEL);
    f4* __restrict__ o1 = (f4*)(out + (size_t)(SEQ + t) * D_MODEL);

    // Issue ALL loads first (20 float4 loads in flight), then combine + store.
    f4 a0[4], a1[4], pv[4], v0[4], v1[4];
#pragma unroll
    for (int k = 0; k < 4; ++k) {
        const int i = tid + k * 256;
        a0[k] = k0[i];
        a1[k] = k1[i];
        pv[k] = pr[i];
        v0[k] = b0[i];
        v1[k] = b1[i];
    }
#pragma unroll
    for (int k = 0; k < 4; ++k) {
        const int i = tid + k * 256;
        f4 r0 = a0[k] + v0[k] + pv[k];
        f4 r1 = a1[k] + v1[k] + pv[k];
        __builtin_nontemporal_store(r0, &o0[i]);
        __builtin_nontemporal_store(r1, &o1[i]);
    }
}

extern "C" void kernel_launch(void* const* d_in, const int* in_sizes, int n_in,
                              void* d_out, int out_size, void* d_ws, size_t ws_size,
                              hipStream_t stream) {
    const int*   x    = (const int*)  d_in[0];   // [BATCH, SEQ]
    const float* kern = (const float*)d_in[1];   // [N_VOCAB, D_MODEL]
    const float* bias = (const float*)d_in[2];   // [D_MODEL]
    const float* pos  = (const float*)d_in[3];   // [SHARDS, SEQ, PER_OUT] == flat [SEQ*D_MODEL]

    float* out  = (float*)d_out;                 // [BATCH, SEQ, D_MODEL]
    float* bsum = (float*)d_ws;                  // [SHARDS][D_MODEL] = 128 KB

    boundary_sums_kernel<<<(D_MODEL + 255) / 256, 256, 0, stream>>>(kern, bias, bsum);

    embed_gather_kernel<<<SEQ, 256, 0, stream>>>(x, kern, pos, bsum, out);
}

// Round 4
// 34.372 us; speedup vs baseline: 1.1433x; 1.0004x over previous
//
#include <hip/hip_runtime.h>

#define N_VOCAB 50400
#define D_MODEL 4096
#define SHARDS  8
#define SEQ     2048
#define BATCH   2
#define PER_IN  6300   // N_VOCAB / SHARDS

typedef float f4 __attribute__((ext_vector_type(4)));

// Kernel 1: bsum[s][d] = sum_{s'<s} kern[s'*PER_IN+PER_IN-1][d]
//                      + sum_{s'>s} kern[s'*PER_IN][d] + SHARDS*bias[d]
// Parallelized over (s, d-chunk): grid = SHARDS * (D_MODEL/4/256) = 32 blocks.
__global__ __launch_bounds__(256)
void boundary_sums_kernel(const float* __restrict__ kern,
                          const float* __restrict__ bias,
                          float* __restrict__ bsum) {
    const int s  = blockIdx.x >> 2;                  // 0..7
    const int c  = blockIdx.x & 3;                   // 0..3
    const int d4 = c * 256 + threadIdx.x;            // f4 column index, 0..1023

    const f4* __restrict__ kf = (const f4*)kern;
    const f4* __restrict__ bf = (const f4*)bias;

    f4 acc = (float)SHARDS * bf[d4];
#pragma unroll
    for (int sp = 0; sp < SHARDS; ++sp) {
        if (sp < s)
            acc += kf[(size_t)(sp * PER_IN + PER_IN - 1) * (D_MODEL / 4) + d4];
        else if (sp > s)
            acc += kf[(size_t)(sp * PER_IN) * (D_MODEL / 4) + d4];
    }
    ((f4*)bsum)[(size_t)s * (D_MODEL / 4) + d4] = acc;
}

// Kernel 2: grid = SEQ*2 blocks; block handles one HALF (2048 dims) of one
// sequence position t, for BOTH batch rows.
// out[b,t,:] = kern[x[b,t]] + bsum[x[b,t]/PER_IN] + pos_flat[t,:]
__global__ __launch_bounds__(256)
void embed_gather_kernel(const int* __restrict__ x,
                         const float* __restrict__ kern,
                         const float* __restrict__ pos,   // flat [SEQ*D_MODEL]
                         const float* __restrict__ bsum,  // [SHARDS][D_MODEL]
                         float* __restrict__ out) {
    const int t    = blockIdx.x >> 1;
    const int half = blockIdx.x & 1;
    const int tid  = threadIdx.x;
    const int base = half * (D_MODEL / 8);   // f4 offset of this half-row (512 f4 per half)

    const int row0 = x[t];           // uniform -> scalar load
    const int row1 = x[SEQ + t];
    const int s0 = row0 / PER_IN;
    const int s1 = row1 / PER_IN;

    const f4* __restrict__ k0 = (const f4*)(kern + (size_t)row0 * D_MODEL) + base;
    const f4* __restrict__ k1 = (const f4*)(kern + (size_t)row1 * D_MODEL) + base;
    const f4* __restrict__ pr = (const f4*)(pos  + (size_t)t    * D_MODEL) + base;
    const f4* __restrict__ b0 = (const f4*)(bsum + (size_t)s0   * D_MODEL) + base;
    const f4* __restrict__ b1 = (const f4*)(bsum + (size_t)s1   * D_MODEL) + base;
    f4* __restrict__ o0 = (f4*)(out + (size_t)t         * D_MODEL) + base;
    f4* __restrict__ o1 = (f4*)(out + (size_t)(SEQ + t) * D_MODEL) + base;

    // 10 loads in flight, then combine + 4 nontemporal stores.
    f4 a0[2], a1[2], pv[2], v0[2], v1[2];
#pragma unroll
    for (int k = 0; k < 2; ++k) {
        const int i = tid + k * 256;
        a0[k] = k0[i];
        a1[k] = k1[i];
        pv[k] = pr[i];
        v0[k] = b0[i];
        v1[k] = b1[i];
    }
#pragma unroll
    for (int k = 0; k < 2; ++k) {
        const int i = tid + k * 256;
        f4 r0 = a0[k] + v0[k] + pv[k];
        f4 r1 = a1[k] + v1[k] + pv[k];
        __builtin_nontemporal_store(r0, &o0[i]);
        __builtin_nontemporal_store(r1, &o1[i]);
    }
}

extern "C" void kernel_launch(void* const* d_in, const int* in_sizes, int n_in,
                              void* d_out, int out_size, void* d_ws, size_t ws_size,
                              hipStream_t stream) {
    const int*   x    = (const int*)  d_in[0];   // [BATCH, SEQ]
    const float* kern = (const float*)d_in[1];   // [N_VOCAB, D_MODEL]
    const float* bias = (const float*)d_in[2];   // [D_MODEL]
    const float* pos  = (const float*)d_in[3];   // [SHARDS, SEQ, PER_OUT] == flat [SEQ*D_MODEL]

    float* out  = (float*)d_out;                 // [BATCH, SEQ, D_MODEL]
    float* bsum = (float*)d_ws;                  // [SHARDS][D_MODEL] = 128 KB

    boundary_sums_kernel<<<SHARDS * (D_MODEL / 4 / 256), 256, 0, stream>>>(kern, bias, bsum);

    embed_gather_kernel<<<SEQ * 2, 256, 0, stream>>>(x, kern, pos, bsum, out);
}